// Round 20
// baseline (318.743 us; speedup 1.0000x reference)
//
#include <hip/hip_runtime.h>

#define NS 4096
#define NT 8192
#define DIN 256
#define DOUT 128

// float offsets into workspace (no zeroing needed: every buffer fully written)
#define OFF_RS    0                            // rs [NS] (final)
#define OFF_RT    (NS)                         // rt [NT] (final)
#define OFF_RS0   (OFF_RT + NT)                // adj_s row sums [NS]
#define OFF_PROW4 (OFF_RS0 + NS)               // adj per-wave row partials [4][NS]
#define OFF_PTT   (OFF_PROW4 + 4*NS)           // adj_t col partials [1024][NT]
#define OFF_PTA   (OFF_PTT + 1024*NT)          // adj col partials [512][NT]
#define OFF_PT2   (OFF_PTA + 512*NT)           // rt 2nd-level partials [12][NT]
#define OFF_C1P   (OFF_PT2 + 12*NT)            // C1 parts [24][NS*DOUT]
#define OFF_C2P   (OFF_C1P + 24*NS*DOUT)       // C2 parts [24][NT*DOUT]
#define OFF_XS    (OFF_C2P + 24*NT*DOUT)
#define OFF_YS    (OFF_XS + NS*DOUT)
#define OFF_XNS   (OFF_YS + NT*DOUT)
#define OFF_XST   (OFF_XNS + NS*DOUT)          // bf16 [128][NS]
#define OFF_YST   (OFF_XST + (128*NS)/2)       // bf16 [128][NT]

typedef __attribute__((ext_vector_type(8))) short bf8v;
typedef __attribute__((ext_vector_type(4))) float f32x4;
typedef __attribute__((ext_vector_type(4))) unsigned short u16x4;

__device__ __forceinline__ ushort f2bf(float f) {
    // exact round-to-nearest-even fp32 -> bf16 (finite inputs only)
    unsigned x = __float_as_uint(f);
    unsigned r = (x + 0x7fffu + ((x >> 16) & 1u)) >> 16;
    return (ushort)r;
}

// Degree pass, atomic-free. The cold HBM-bound adj_t stream gets the MOST
// blocks and dispatches FIRST (its tail was running at ~2 blocks/CU).
// bids [0,1024):    adj_t colsum, 8 rows -> ptt[1024][NT]
// bids [1024,1536): adj fused col+row, 8 rows -> pta[512][NT], prow4[4][NS]
// bids [1536,2560): adj_s rowsum, 4 rows -> rs0[NS]   (L3-warm, drains fast)
__global__ __launch_bounds__(256)
void deg_mega_kernel(const float* __restrict__ adj,
                     const float* __restrict__ adj_s,
                     const float* __restrict__ adj_t,
                     float* __restrict__ rs0, float* __restrict__ prow4,
                     float* __restrict__ ptt, float* __restrict__ pta) {
    const int tid = threadIdx.x;
    const int lane = tid & 63;
    const int wid = tid >> 6;
    const int bid = blockIdx.x;
    if (bid < 1024) {
        const int r0 = bid * 8;
        const float4* A4 = (const float4*)adj_t + (size_t)r0 * (NT / 4);
        float4 acc[8];
#pragma unroll
        for (int it = 0; it < 8; ++it) acc[it] = make_float4(0.f, 0.f, 0.f, 0.f);
        for (int r = 0; r < 8; ++r) {
            const float4* Row = A4 + (size_t)r * (NT / 4);
#pragma unroll
            for (int it = 0; it < 8; ++it) {
                float4 v = Row[it * 256 + tid];
                acc[it].x += v.x; acc[it].y += v.y; acc[it].z += v.z; acc[it].w += v.w;
            }
        }
#pragma unroll
        for (int it = 0; it < 8; ++it)
            *(float4*)&ptt[(size_t)bid * NT + (it * 256 + tid) * 4] = acc[it];
    } else if (bid < 1536) {
        const int b = bid - 1024;
        const int r0 = b * 8;
        const float4* A4 = (const float4*)adj + (size_t)r0 * (NT / 4);
        float4 acc[8];
#pragma unroll
        for (int it = 0; it < 8; ++it) acc[it] = make_float4(0.f, 0.f, 0.f, 0.f);
        for (int r = 0; r < 8; ++r) {
            const float4* Row = A4 + (size_t)r * (NT / 4);
            float rsum = 0.f;
#pragma unroll
            for (int it = 0; it < 8; ++it) {
                float4 v = Row[it * 256 + tid];
                acc[it].x += v.x; acc[it].y += v.y; acc[it].z += v.z; acc[it].w += v.w;
                rsum += v.x + v.y + v.z + v.w;
            }
#pragma unroll
            for (int off = 32; off > 0; off >>= 1) rsum += __shfl_down(rsum, off, 64);
            if (lane == 0) prow4[(size_t)wid * NS + r0 + r] = rsum;   // unique (wave,row)
        }
#pragma unroll
        for (int it = 0; it < 8; ++it)
            *(float4*)&pta[(size_t)b * NT + (it * 256 + tid) * 4] = acc[it];
    } else {
        const int b = bid - 1536;
        const int row = b * 4 + wid;
        const float4* p = (const float4*)(adj_s + (size_t)row * NS);
        float sum = 0.f;
#pragma unroll 8
        for (int c = lane; c < NS / 4; c += 64) { float4 v = p[c]; sum += v.x + v.y + v.z + v.w; }
#pragma unroll
        for (int off = 32; off > 0; off >>= 1) sum += __shfl_down(sum, off, 64);
        if (lane == 0) rs0[row] = sum;
    }
}

// Level-1 rt reduction: block (cb, pb) sums parts [pb*128,(pb+1)*128) of the
// 1536 combined {ptt,pta} parts for 256 columns -> pt2[pb][NT].
__global__ __launch_bounds__(256)
void finish_rt1_kernel(const float* __restrict__ ptt, const float* __restrict__ pta,
                       float* __restrict__ pt2) {
    const int c = blockIdx.x * 256 + threadIdx.x;
    const int pb = blockIdx.y;
    float s = 0.f;
    const int p0 = pb * 128;
#pragma unroll 8
    for (int p = p0; p < p0 + 128; ++p)
        s += (p < 1024) ? ptt[(size_t)p * NT + c] : pta[(size_t)(p - 1024) * NT + c];
    pt2[(size_t)pb * NT + c] = s;
}

// rs[i] = sqrt(rs0 + sum4 prow4 + 1); rt[c] = sqrt(sum12 pt2 + 1)
__global__ void finish_all_kernel(const float* __restrict__ rs0,
                                  const float* __restrict__ prow4,
                                  const float* __restrict__ pt2,
                                  float* __restrict__ rs, float* __restrict__ rt) {
    int t = blockIdx.x * blockDim.x + threadIdx.x;
    if (t < NS) {
        float s = rs0[t];
#pragma unroll
        for (int i = 0; i < 4; ++i) s += prow4[(size_t)i * NS + t];
        rs[t] = sqrtf(s + 1.0f);
    } else if (t < NS + NT) {
        int c = t - NS;
        float s = 0.f;
#pragma unroll
        for (int i = 0; i < 12; ++i) s += pt2[(size_t)i * NT + c];
        rt[c] = sqrtf(s + 1.0f);
    }
}

// Both projections in one launch: out[m,:] = (inp[m,:]@W)/rdeg[m] (fp32)
// plus outT[n][m] = bf16(out[m][n]).  bids [0,NS/64) -> s-side, rest -> t-side.
__global__ __launch_bounds__(256)
void proj_scale_kernel(const float* __restrict__ inp_s,
                       const float* __restrict__ inp_t,
                       const float* __restrict__ W,
                       const float* __restrict__ rs, const float* __restrict__ rt,
                       float* __restrict__ xs, float* __restrict__ ys,
                       ushort* __restrict__ xsT, ushort* __restrict__ ysT) {
    __shared__ float As[32][68];
    __shared__ float Bs[32][128];
    const int tid = threadIdx.x;

    const float* inp; const float* rdeg; float* outp; ushort* outT; int M; int m0;
    if (blockIdx.x < NS / 64) {
        inp = inp_s; rdeg = rs; outp = xs; outT = xsT; M = NS; m0 = blockIdx.x * 64;
    } else {
        int b = blockIdx.x - NS / 64;
        inp = inp_t; rdeg = rt; outp = ys; outT = ysT; M = NT; m0 = b * 64;
    }

    const int tx = tid & 15, ty = tid >> 4;
    const int arow = tid >> 3, acg = tid & 7;
    const int bk = tid >> 5, bng = tid & 31;

    float acc[4][8];
#pragma unroll
    for (int r = 0; r < 4; ++r)
#pragma unroll
        for (int c = 0; c < 8; ++c) acc[r][c] = 0.f;

    for (int kt = 0; kt < DIN; kt += 32) {
        const float* Ab = inp + (size_t)(m0 + arow) * DIN + kt + acg * 4;
        float4 a0 = *(const float4*)Ab;
        float4 a1 = *(const float4*)(Ab + (size_t)32 * DIN);
        const float* Bb = W + (size_t)(kt + bk) * DOUT + bng * 4;
        float4 b0 = *(const float4*)Bb;
        float4 b1 = *(const float4*)(Bb + 8 * DOUT);
        float4 b2 = *(const float4*)(Bb + 16 * DOUT);
        float4 b3 = *(const float4*)(Bb + 24 * DOUT);
        __syncthreads();
        As[acg * 4 + 0][arow] = a0.x;
        As[acg * 4 + 1][arow] = a0.y;
        As[acg * 4 + 2][arow] = a0.z;
        As[acg * 4 + 3][arow] = a0.w;
        As[acg * 4 + 0][arow + 32] = a1.x;
        As[acg * 4 + 1][arow + 32] = a1.y;
        As[acg * 4 + 2][arow + 32] = a1.z;
        As[acg * 4 + 3][arow + 32] = a1.w;
        *(float4*)&Bs[bk][bng * 4] = b0;
        *(float4*)&Bs[bk + 8][bng * 4] = b1;
        *(float4*)&Bs[bk + 16][bng * 4] = b2;
        *(float4*)&Bs[bk + 24][bng * 4] = b3;
        __syncthreads();
#pragma unroll
        for (int k = 0; k < 32; ++k) {
            float4 av = *(const float4*)&As[k][ty * 4];
            float4 bv0 = *(const float4*)&Bs[k][tx * 4];
            float4 bv1 = *(const float4*)&Bs[k][tx * 4 + 64];
            float a[4] = {av.x, av.y, av.z, av.w};
            float b[8] = {bv0.x, bv0.y, bv0.z, bv0.w, bv1.x, bv1.y, bv1.z, bv1.w};
#pragma unroll
            for (int r = 0; r < 4; ++r)
#pragma unroll
                for (int c = 0; c < 8; ++c) acc[r][c] = fmaf(a[r], b[c], acc[r][c]);
        }
    }
    float rds[4];
#pragma unroll
    for (int r = 0; r < 4; ++r) rds[r] = rdeg[m0 + ty * 4 + r];
#pragma unroll
    for (int r = 0; r < 4; ++r) {
        int row = m0 + ty * 4 + r;
        float* orow = outp + (size_t)row * DOUT;
#pragma unroll
        for (int c = 0; c < 8; ++c) acc[r][c] /= rds[r];
#pragma unroll
        for (int c = 0; c < 4; ++c) {
            orow[tx * 4 + c] = acc[r][c];
            orow[tx * 4 + 64 + c] = acc[r][4 + c];
        }
    }
#pragma unroll
    for (int c = 0; c < 8; ++c) {
        int col = tx * 4 + (c & 3) + (c >> 2) * 64;
        u16x4 w;
#pragma unroll
        for (int r = 0; r < 4; ++r) w[r] = f2bf(acc[r][c]);
        *(u16x4*)&outT[(size_t)col * M + m0 + ty * 4] = w;
    }
}

// One 128x128 output tile over one K-chunk. C is this split's PRIVATE part buffer:
// plain stores, exact coverage, no atomics, no zeroing.
template<int TRANS, int BTF>
__device__ __forceinline__
void gemm_body(ushort (*As)[40], ushort (*Bs)[40],
               const float* __restrict__ A, int lda,
               const float* __restrict__ Bf,
               const ushort* __restrict__ bT, int ldb,
               float* __restrict__ C, int kchunk, int k0, int m0) {
    const int tid = threadIdx.x;
    const int lane = tid & 63, wid = tid >> 6;
    const int wm = (wid >> 1) * 64, wn = (wid & 1) * 64;
    const int r16 = lane & 15, kg = lane >> 4;

    const int s_kr = tid >> 3, s_f4 = tid & 7;   // fp32-B / TRANS-A staging map
    const int a_r = tid >> 1, a_seg = tid & 1;   // NN-A staging map
    const int t_n = tid >> 2, t_seg = tid & 3;   // bf16-T B staging map

    f32x4 acc[4][4];
#pragma unroll
    for (int i = 0; i < 4; ++i)
#pragma unroll
        for (int j = 0; j < 4; ++j) acc[i][j] = (f32x4)(0.f);

    float4 aP[4], bP[4];
    bf8v bPT[2];

    auto loadB = [&](int ktb) {
        if (BTF) {
            const ushort* Tb = bT + (size_t)t_n * ldb + k0 + ktb + t_seg * 8;
            bPT[0] = *(const bf8v*)Tb;
            bPT[1] = *(const bf8v*)(Tb + (size_t)64 * ldb);
        } else {
            const float* Bb = Bf + (size_t)(k0 + ktb + s_kr) * DOUT + s_f4 * 4;
#pragma unroll
            for (int i = 0; i < 4; ++i) bP[i] = *(const float4*)(Bb + i * 32);
        }
    };
    auto loadA = [&](int ktb) {
        if (TRANS) {
            const float* Ab = A + (size_t)(k0 + ktb + s_kr) * lda + m0 + s_f4 * 4;
#pragma unroll
            for (int i = 0; i < 4; ++i) aP[i] = *(const float4*)(Ab + i * 32);
        } else {
            const float* Ab = A + (size_t)(m0 + a_r) * lda + k0 + ktb + a_seg * 16;
#pragma unroll
            for (int i = 0; i < 4; ++i) aP[i] = *(const float4*)(Ab + i * 4);
        }
    };

    loadB(0); loadA(0);

    for (int kt = 0; kt < kchunk; kt += 32) {
        __syncthreads();
        if (TRANS) {
#pragma unroll
            for (int i = 0; i < 4; ++i) {
                int m = s_f4 * 4 + i * 32;
                As[m + 0][s_kr] = f2bf(aP[i].x);
                As[m + 1][s_kr] = f2bf(aP[i].y);
                As[m + 2][s_kr] = f2bf(aP[i].z);
                As[m + 3][s_kr] = f2bf(aP[i].w);
            }
        } else {
            bf8v w0, w1;
            w0[0] = (short)f2bf(aP[0].x); w0[1] = (short)f2bf(aP[0].y);
            w0[2] = (short)f2bf(aP[0].z); w0[3] = (short)f2bf(aP[0].w);
            w0[4] = (short)f2bf(aP[1].x); w0[5] = (short)f2bf(aP[1].y);
            w0[6] = (short)f2bf(aP[1].z); w0[7] = (short)f2bf(aP[1].w);
            w1[0] = (short)f2bf(aP[2].x); w1[1] = (short)f2bf(aP[2].y);
            w1[2] = (short)f2bf(aP[2].z); w1[3] = (short)f2bf(aP[2].w);
            w1[4] = (short)f2bf(aP[3].x); w1[5] = (short)f2bf(aP[3].y);
            w1[6] = (short)f2bf(aP[3].z); w1[7] = (short)f2bf(aP[3].w);
            *(bf8v*)&As[a_r][a_seg * 16] = w0;
            *(bf8v*)&As[a_r][a_seg * 16 + 8] = w1;
        }
        if (BTF) {
            *(bf8v*)&Bs[t_n][t_seg * 8] = bPT[0];
            *(bf8v*)&Bs[t_n + 64][t_seg * 8] = bPT[1];
        } else {
#pragma unroll
            for (int i = 0; i < 4; ++i) {
                int n = s_f4 * 4 + i * 32;
                Bs[n + 0][s_kr] = f2bf(bP[i].x);
                Bs[n + 1][s_kr] = f2bf(bP[i].y);
                Bs[n + 2][s_kr] = f2bf(bP[i].z);
                Bs[n + 3][s_kr] = f2bf(bP[i].w);
            }
        }
        __syncthreads();

        if (kt + 32 < kchunk) { loadB(kt + 32); loadA(kt + 32); }

        bf8v af[4], bfv[4];
#pragma unroll
        for (int f = 0; f < 4; ++f) af[f] = *(const bf8v*)&As[wm + f * 16 + r16][kg * 8];
#pragma unroll
        for (int f = 0; f < 4; ++f) bfv[f] = *(const bf8v*)&Bs[wn + f * 16 + r16][kg * 8];
#pragma unroll
        for (int i = 0; i < 4; ++i)
#pragma unroll
            for (int j = 0; j < 4; ++j)
                acc[i][j] = __builtin_amdgcn_mfma_f32_16x16x32_bf16(af[i], bfv[j], acc[i][j], 0, 0, 0);
    }

    const int crow0 = m0 + wm + (lane >> 4) * 4;
#pragma unroll
    for (int i = 0; i < 4; ++i) {
#pragma unroll
        for (int j = 0; j < 4; ++j) {
            float* base = C + (size_t)(crow0 + i * 16) * DOUT + wn + j * 16 + r16;
            base[0 * DOUT] = acc[i][j][0];
            base[1 * DOUT] = acc[i][j][1];
            base[2 * DOUT] = acc[i][j][2];
            base[3 * DOUT] = acc[i][j][3];
        }
    }
}

// Three independent GEMMs co-scheduled, UNIFORM kchunk=512 per block (no tail skew):
// bids [0,256):     adj_s@xs -> C1P[0..8)    (32 mtiles x 8 splits,  k=512)
// bids [256,768):   adj@ys   -> C1P[8..24)   (32 mtiles x 16 splits, k=512)
// bids [768,1792):  adj_t@ys -> C2P[0..16)   (64 mtiles x 16 splits, k=512)
__global__ __launch_bounds__(256)
void gemm_triple_kernel(const float* __restrict__ adj_s,
                        const float* __restrict__ adj,
                        const float* __restrict__ adj_t,
                        const ushort* __restrict__ xsT,
                        const ushort* __restrict__ ysT,
                        float* __restrict__ C1P, float* __restrict__ C2P) {
    __shared__ ushort As[128][40];
    __shared__ ushort Bs[128][40];
    int bid = blockIdx.x;
    if (bid < 256) {
        int s = bid & 7;
        gemm_body<0, 1>(As, Bs, adj_s, NS, nullptr, xsT, NS,
                        C1P + (size_t)s * (NS * DOUT), NS / 8, s * (NS / 8), (bid >> 3) * 128);
    } else if (bid < 768) {
        int b = bid - 256, s = b & 15;
        gemm_body<0, 1>(As, Bs, adj, NT, nullptr, ysT, NT,
                        C1P + (size_t)(8 + s) * (NS * DOUT), NT / 16, s * (NT / 16), (b >> 4) * 128);
    } else {
        int b = bid - 768, s = b & 15;
        gemm_body<0, 1>(As, Bs, adj_t, NT, nullptr, ysT, NT,
                        C2P + (size_t)s * (NT * DOUT), NT / 16, s * (NT / 16), (b >> 4) * 128);
    }
}

// Dependent adj^T @ xns -> C2P[16..24), kchunk=512 (8 splits)
__global__ __launch_bounds__(256)
void gemm_trans_kernel(const float* __restrict__ adj,
                       const float* __restrict__ xns,
                       float* __restrict__ C2P) {
    __shared__ ushort As[128][40];
    __shared__ ushort Bs[128][40];
    int s = blockIdx.y;
    gemm_body<1, 0>(As, Bs, adj, NT, xns, nullptr, 0,
                    C2P + (size_t)(16 + s) * (NT * DOUT), NS / 8, s * (NS / 8), blockIdx.x * 128);
}

// x_new = relu(xs + (sum24 C1P)/rs) -> d_out;  xns = x_new/rs (float4)
__global__ void epilogue1_kernel(const float* __restrict__ C1P,
                                 const float* __restrict__ xs,
                                 const float* __restrict__ rs,
                                 float* __restrict__ outx,
                                 float* __restrict__ xns) {
    int i4 = blockIdx.x * blockDim.x + threadIdx.x;
    if (i4 >= NS * DOUT / 4) return;
    float4 s = ((const float4*)C1P)[i4];
#pragma unroll
    for (int p = 1; p < 24; ++p) {
        float4 v = ((const float4*)(C1P + (size_t)p * (NS * DOUT)))[i4];
        s.x += v.x; s.y += v.y; s.z += v.z; s.w += v.w;
    }
    float r = rs[i4 >> 5];   // (i4*4) / 128
    float4 x = ((const float4*)xs)[i4];
    float4 o, n;
    o.x = fmaxf(x.x + s.x / r, 0.f); n.x = o.x / r;
    o.y = fmaxf(x.y + s.y / r, 0.f); n.y = o.y / r;
    o.z = fmaxf(x.z + s.z / r, 0.f); n.z = o.z / r;
    o.w = fmaxf(x.w + s.w / r, 0.f); n.w = o.w / r;
    ((float4*)outx)[i4] = o;
    ((float4*)xns)[i4] = n;
}

// y_new = relu(ys + (sum24 C2P)/rt) -> d_out + NS*DOUT (float4)
__global__ void epilogue2_kernel(const float* __restrict__ C2P,
                                 const float* __restrict__ ys,
                                 const float* __restrict__ rt,
                                 float* __restrict__ outy) {
    int i4 = blockIdx.x * blockDim.x + threadIdx.x;
    if (i4 >= NT * DOUT / 4) return;
    float4 s = ((const float4*)C2P)[i4];
#pragma unroll
    for (int p = 1; p < 24; ++p) {
        float4 v = ((const float4*)(C2P + (size_t)p * (NT * DOUT)))[i4];
        s.x += v.x; s.y += v.y; s.z += v.z; s.w += v.w;
    }
    float r = rt[i4 >> 5];
    float4 y = ((const float4*)ys)[i4];
    float4 o;
    o.x = fmaxf(y.x + s.x / r, 0.f);
    o.y = fmaxf(y.y + s.y / r, 0.f);
    o.z = fmaxf(y.z + s.z / r, 0.f);
    o.w = fmaxf(y.w + s.w / r, 0.f);
    ((float4*)outy)[i4] = o;
}

extern "C" void kernel_launch(void* const* d_in, const int* in_sizes, int n_in,
                              void* d_out, int out_size, void* d_ws, size_t ws_size,
                              hipStream_t stream) {
    const float* inp_s = (const float*)d_in[0];
    const float* inp_t = (const float*)d_in[1];
    const float* adj   = (const float*)d_in[2];
    const float* adj_s = (const float*)d_in[3];
    const float* adj_t = (const float*)d_in[4];
    const float* W     = (const float*)d_in[5];
    float* out = (float*)d_out;
    float* ws  = (float*)d_ws;

    float* rs    = ws + OFF_RS;
    float* rt    = ws + OFF_RT;
    float* rs0   = ws + OFF_RS0;
    float* prow4 = ws + OFF_PROW4;
    float* ptt   = ws + OFF_PTT;
    float* pta   = ws + OFF_PTA;
    float* pt2   = ws + OFF_PT2;
    float* C1P   = ws + OFF_C1P;
    float* C2P   = ws + OFF_C2P;
    float* xs    = ws + OFF_XS;
    float* ys    = ws + OFF_YS;
    float* xns   = ws + OFF_XNS;
    ushort* xsT  = (ushort*)(ws + OFF_XST);
    ushort* ysT  = (ushort*)(ws + OFF_YST);

    // Degree pass: HBM-bound adj_t stream gets 1024 blocks and launches first.
    deg_mega_kernel<<<2560, 256, 0, stream>>>(adj, adj_s, adj_t, rs0, prow4, ptt, pta);
    finish_rt1_kernel<<<dim3(NT / 256, 12), 256, 0, stream>>>(ptt, pta, pt2);
    finish_all_kernel<<<(NS + NT) / 256, 256, 0, stream>>>(rs0, prow4, pt2, rs, rt);

    // Both projections in one launch: xs/xsT and ys/ysT
    proj_scale_kernel<<<(NS + NT) / 64, 256, 0, stream>>>(inp_s, inp_t, W, rs, rt, xs, ys, xsT, ysT);

    // Phase A: three GEMMs, uniform 512-K blocks, 1792 blocks = 7/CU.
    gemm_triple_kernel<<<1792, 256, 0, stream>>>(adj_s, adj, adj_t, xsT, ysT, C1P, C2P);
    epilogue1_kernel<<<(NS * DOUT / 4 + 255) / 256, 256, 0, stream>>>(C1P, xs, rs, out, xns);

    // Phase B: dependent adj^T @ xns -> C2P[16..24), 512 blocks.
    gemm_trans_kernel<<<dim3(NT / 128, 8), 256, 0, stream>>>(adj, xns, C2P);
    epilogue2_kernel<<<(NT * DOUT / 4 + 255) / 256, 256, 0, stream>>>(C2P, ys, rt, out + NS * DOUT);
}

// Round 21
// 290.131 us; speedup vs baseline: 1.0986x; 1.0986x over previous
//
#include <hip/hip_runtime.h>

#define NS 4096
#define NT 8192
#define DIN 256
#define DOUT 128

// float offsets into workspace (no zeroing needed: every buffer fully written)
#define OFF_RS    0                            // rs [NS] (final)
#define OFF_RT    (NS)                         // rt [NT] (final)
#define OFF_RS0   (OFF_RT + NT)                // adj_s row sums [NS]
#define OFF_PROW4 (OFF_RS0 + NS)               // adj per-wave row partials [4][NS]
#define OFF_PTT   (OFF_PROW4 + 4*NS)           // adj_t col partials [512][NT]
#define OFF_PTA   (OFF_PTT + 512*NT)           // adj col partials [256][NT]
#define OFF_PT2   (OFF_PTA + 256*NT)           // rt 2nd-level partials [12][NT]
#define OFF_C1P   (OFF_PT2 + 12*NT)            // C1 parts [24][NS*DOUT]
#define OFF_C2P   (OFF_C1P + 24*NS*DOUT)       // C2 parts [24][NT*DOUT]
#define OFF_XS    (OFF_C2P + 24*NT*DOUT)
#define OFF_YS    (OFF_XS + NS*DOUT)
#define OFF_XNS   (OFF_YS + NT*DOUT)
#define OFF_XST   (OFF_XNS + NS*DOUT)          // bf16 [128][NS]
#define OFF_YST   (OFF_XST + (128*NS)/2)       // bf16 [128][NT]
#define OFF_US    (OFF_YST + (128*NT)/2)       // unscaled proj u_s [NS][DOUT]
#define OFF_UT    (OFF_US + NS*DOUT)           // unscaled proj u_t [NT][DOUT]

typedef __attribute__((ext_vector_type(8))) short bf8v;
typedef __attribute__((ext_vector_type(4))) float f32x4;
typedef __attribute__((ext_vector_type(4))) unsigned short u16x4;

__device__ __forceinline__ ushort f2bf(float f) {
    // exact round-to-nearest-even fp32 -> bf16 (finite inputs only)
    unsigned x = __float_as_uint(f);
    unsigned r = (x + 0x7fffu + ((x >> 16) & 1u)) >> 16;
    return (ushort)r;
}

// Degree pass + unscaled projection, co-scheduled (the projection GEMM does not
// depend on degrees; only the later scaling does).
// bids [0,512):     adj_t colsum, 16 rows -> ptt[512][NT]  (nt loads)
// bids [512,768):   adj fused col+row, 16 rows -> pta[256][NT], prow4[4][NS]
// bids [768,1792):  adj_s rowsum, 4 rows -> rs0[NS]
// bids [1792,1984): u = inp@W (unscaled proj; 64 s-blocks + 128 t-blocks)
__global__ __launch_bounds__(256)
void deg_mega_kernel(const float* __restrict__ adj,
                     const float* __restrict__ adj_s,
                     const float* __restrict__ adj_t,
                     const float* __restrict__ inp_s,
                     const float* __restrict__ inp_t,
                     const float* __restrict__ W,
                     float* __restrict__ rs0, float* __restrict__ prow4,
                     float* __restrict__ ptt, float* __restrict__ pta,
                     float* __restrict__ u_s, float* __restrict__ u_t) {
    __shared__ float As[32][68];
    __shared__ float Bs[32][128];
    const int tid = threadIdx.x;
    const int lane = tid & 63;
    const int wid = tid >> 6;
    const int bid = blockIdx.x;
    if (bid < 512) {
        const int r0 = bid * 16;
        const f32x4* A4 = (const f32x4*)adj_t + (size_t)r0 * (NT / 4);
        f32x4 acc[8];
#pragma unroll
        for (int it = 0; it < 8; ++it) acc[it] = (f32x4)(0.f);
        for (int r = 0; r < 16; ++r) {
            const f32x4* Row = A4 + (size_t)r * (NT / 4);
#pragma unroll
            for (int it = 0; it < 8; ++it) {
                f32x4 v = __builtin_nontemporal_load(&Row[it * 256 + tid]);
                acc[it] += v;
            }
        }
#pragma unroll
        for (int it = 0; it < 8; ++it)
            *(f32x4*)&ptt[(size_t)bid * NT + (it * 256 + tid) * 4] = acc[it];
    } else if (bid < 768) {
        const int b = bid - 512;
        const int r0 = b * 16;
        const float4* A4 = (const float4*)adj + (size_t)r0 * (NT / 4);
        float4 acc[8];
#pragma unroll
        for (int it = 0; it < 8; ++it) acc[it] = make_float4(0.f, 0.f, 0.f, 0.f);
        for (int r = 0; r < 16; ++r) {
            const float4* Row = A4 + (size_t)r * (NT / 4);
            float rsum = 0.f;
#pragma unroll
            for (int it = 0; it < 8; ++it) {
                float4 v = Row[it * 256 + tid];
                acc[it].x += v.x; acc[it].y += v.y; acc[it].z += v.z; acc[it].w += v.w;
                rsum += v.x + v.y + v.z + v.w;
            }
#pragma unroll
            for (int off = 32; off > 0; off >>= 1) rsum += __shfl_down(rsum, off, 64);
            if (lane == 0) prow4[(size_t)wid * NS + r0 + r] = rsum;   // unique (wave,row)
        }
#pragma unroll
        for (int it = 0; it < 8; ++it)
            *(float4*)&pta[(size_t)b * NT + (it * 256 + tid) * 4] = acc[it];
    } else if (bid < 1792) {
        const int b = bid - 768;
        const int row = b * 4 + wid;
        const float4* p = (const float4*)(adj_s + (size_t)row * NS);
        float sum = 0.f;
#pragma unroll 8
        for (int c = lane; c < NS / 4; c += 64) { float4 v = p[c]; sum += v.x + v.y + v.z + v.w; }
#pragma unroll
        for (int off = 32; off > 0; off >>= 1) sum += __shfl_down(sum, off, 64);
        if (lane == 0) rs0[row] = sum;
    } else {
        // unscaled projection u = inp @ W  (64x128 tile per block)
        const int b = bid - 1792;
        const float* inp; float* up; int m0;
        if (b < NS / 64) { inp = inp_s; up = u_s; m0 = b * 64; }
        else             { inp = inp_t; up = u_t; m0 = (b - NS / 64) * 64; }

        const int tx = tid & 15, ty = tid >> 4;
        const int arow = tid >> 3, acg = tid & 7;
        const int bk = tid >> 5, bng = tid & 31;

        float acc[4][8];
#pragma unroll
        for (int r = 0; r < 4; ++r)
#pragma unroll
            for (int c = 0; c < 8; ++c) acc[r][c] = 0.f;

        for (int kt = 0; kt < DIN; kt += 32) {
            const float* Ab = inp + (size_t)(m0 + arow) * DIN + kt + acg * 4;
            float4 a0 = *(const float4*)Ab;
            float4 a1 = *(const float4*)(Ab + (size_t)32 * DIN);
            const float* Bb = W + (size_t)(kt + bk) * DOUT + bng * 4;
            float4 b0 = *(const float4*)Bb;
            float4 b1 = *(const float4*)(Bb + 8 * DOUT);
            float4 b2 = *(const float4*)(Bb + 16 * DOUT);
            float4 b3 = *(const float4*)(Bb + 24 * DOUT);
            __syncthreads();
            As[acg * 4 + 0][arow] = a0.x;
            As[acg * 4 + 1][arow] = a0.y;
            As[acg * 4 + 2][arow] = a0.z;
            As[acg * 4 + 3][arow] = a0.w;
            As[acg * 4 + 0][arow + 32] = a1.x;
            As[acg * 4 + 1][arow + 32] = a1.y;
            As[acg * 4 + 2][arow + 32] = a1.z;
            As[acg * 4 + 3][arow + 32] = a1.w;
            *(float4*)&Bs[bk][bng * 4] = b0;
            *(float4*)&Bs[bk + 8][bng * 4] = b1;
            *(float4*)&Bs[bk + 16][bng * 4] = b2;
            *(float4*)&Bs[bk + 24][bng * 4] = b3;
            __syncthreads();
#pragma unroll
            for (int k = 0; k < 32; ++k) {
                float4 av = *(const float4*)&As[k][ty * 4];
                float4 bv0 = *(const float4*)&Bs[k][tx * 4];
                float4 bv1 = *(const float4*)&Bs[k][tx * 4 + 64];
                float a[4] = {av.x, av.y, av.z, av.w};
                float bb[8] = {bv0.x, bv0.y, bv0.z, bv0.w, bv1.x, bv1.y, bv1.z, bv1.w};
#pragma unroll
                for (int r = 0; r < 4; ++r)
#pragma unroll
                    for (int c = 0; c < 8; ++c) acc[r][c] = fmaf(a[r], bb[c], acc[r][c]);
            }
        }
#pragma unroll
        for (int r = 0; r < 4; ++r) {
            int row = m0 + ty * 4 + r;
            float* orow = up + (size_t)row * DOUT;
#pragma unroll
            for (int c = 0; c < 4; ++c) {
                orow[tx * 4 + c] = acc[r][c];
                orow[tx * 4 + 64 + c] = acc[r][4 + c];
            }
        }
    }
}

// Level-1 rt reduction: block (cb, pb) sums parts [pb*64,(pb+1)*64) of the 768
// combined {ptt,pta} parts for 256 columns -> pt2[pb][NT].  Coalesced reads.
__global__ __launch_bounds__(256)
void finish_rt1_kernel(const float* __restrict__ ptt, const float* __restrict__ pta,
                       float* __restrict__ pt2) {
    const int c = blockIdx.x * 256 + threadIdx.x;
    const int pb = blockIdx.y;
    float s = 0.f;
    const int p0 = pb * 64;
#pragma unroll 8
    for (int p = p0; p < p0 + 64; ++p)
        s += (p < 512) ? ptt[(size_t)p * NT + c] : pta[(size_t)(p - 512) * NT + c];
    pt2[(size_t)pb * NT + c] = s;
}

// rs[i] = sqrt(rs0 + sum4 prow4 + 1); rt[c] = sqrt(sum12 pt2 + 1)
__global__ void finish_all_kernel(const float* __restrict__ rs0,
                                  const float* __restrict__ prow4,
                                  const float* __restrict__ pt2,
                                  float* __restrict__ rs, float* __restrict__ rt) {
    int t = blockIdx.x * blockDim.x + threadIdx.x;
    if (t < NS) {
        float s = rs0[t];
#pragma unroll
        for (int i = 0; i < 4; ++i) s += prow4[(size_t)i * NS + t];
        rs[t] = sqrtf(s + 1.0f);
    } else if (t < NS + NT) {
        int c = t - NS;
        float s = 0.f;
#pragma unroll
        for (int i = 0; i < 12; ++i) s += pt2[(size_t)i * NT + c];
        rt[c] = sqrtf(s + 1.0f);
    }
}

// Scale pass: xs = u/rdeg (fp32 rows) + xsT[col][m] = bf16(xs) (transposed).
// 64x128 tile per block; bids [0,NS/64) -> s-side, rest -> t-side.
__global__ __launch_bounds__(256)
void scale_kernel(const float* __restrict__ u_s, const float* __restrict__ u_t,
                  const float* __restrict__ rs, const float* __restrict__ rt,
                  float* __restrict__ xs, float* __restrict__ ys,
                  ushort* __restrict__ xsT, ushort* __restrict__ ysT) {
    const int tid = threadIdx.x;
    const float* up; const float* rdeg; float* outp; ushort* outT; int M; int m0;
    if (blockIdx.x < NS / 64) {
        up = u_s; rdeg = rs; outp = xs; outT = xsT; M = NS; m0 = blockIdx.x * 64;
    } else {
        int b = blockIdx.x - NS / 64;
        up = u_t; rdeg = rt; outp = ys; outT = ysT; M = NT; m0 = b * 64;
    }
    const int tx = tid & 15, ty = tid >> 4;

    float acc[4][8];
    float rds[4];
#pragma unroll
    for (int r = 0; r < 4; ++r) {
        int row = m0 + ty * 4 + r;
        rds[r] = rdeg[row];
        const float* urow = up + (size_t)row * DOUT;
        float4 v0 = *(const float4*)(urow + tx * 4);
        float4 v1 = *(const float4*)(urow + tx * 4 + 64);
        acc[r][0] = v0.x / rds[r]; acc[r][1] = v0.y / rds[r];
        acc[r][2] = v0.z / rds[r]; acc[r][3] = v0.w / rds[r];
        acc[r][4] = v1.x / rds[r]; acc[r][5] = v1.y / rds[r];
        acc[r][6] = v1.z / rds[r]; acc[r][7] = v1.w / rds[r];
    }
#pragma unroll
    for (int r = 0; r < 4; ++r) {
        int row = m0 + ty * 4 + r;
        float* orow = outp + (size_t)row * DOUT;
#pragma unroll
        for (int c = 0; c < 4; ++c) {
            orow[tx * 4 + c] = acc[r][c];
            orow[tx * 4 + 64 + c] = acc[r][4 + c];
        }
    }
#pragma unroll
    for (int c = 0; c < 8; ++c) {
        int col = tx * 4 + (c & 3) + (c >> 2) * 64;
        u16x4 w;
#pragma unroll
        for (int r = 0; r < 4; ++r) w[r] = f2bf(acc[r][c]);
        *(u16x4*)&outT[(size_t)col * M + m0 + ty * 4] = w;
    }
}

// One 128x128 output tile over one K-chunk. C is this split's PRIVATE part buffer:
// plain stores, exact coverage, no atomics, no zeroing.
template<int TRANS, int BTF>
__device__ __forceinline__
void gemm_body(ushort (*As)[40], ushort (*Bs)[40],
               const float* __restrict__ A, int lda,
               const float* __restrict__ Bf,
               const ushort* __restrict__ bT, int ldb,
               float* __restrict__ C, int kchunk, int k0, int m0) {
    const int tid = threadIdx.x;
    const int lane = tid & 63, wid = tid >> 6;
    const int wm = (wid >> 1) * 64, wn = (wid & 1) * 64;
    const int r16 = lane & 15, kg = lane >> 4;

    const int s_kr = tid >> 3, s_f4 = tid & 7;   // fp32-B / TRANS-A staging map
    const int a_r = tid >> 1, a_seg = tid & 1;   // NN-A staging map
    const int t_n = tid >> 2, t_seg = tid & 3;   // bf16-T B staging map

    f32x4 acc[4][4];
#pragma unroll
    for (int i = 0; i < 4; ++i)
#pragma unroll
        for (int j = 0; j < 4; ++j) acc[i][j] = (f32x4)(0.f);

    float4 aP[4], bP[4];
    bf8v bPT[2];

    auto loadB = [&](int ktb) {
        if (BTF) {
            const ushort* Tb = bT + (size_t)t_n * ldb + k0 + ktb + t_seg * 8;
            bPT[0] = *(const bf8v*)Tb;
            bPT[1] = *(const bf8v*)(Tb + (size_t)64 * ldb);
        } else {
            const float* Bb = Bf + (size_t)(k0 + ktb + s_kr) * DOUT + s_f4 * 4;
#pragma unroll
            for (int i = 0; i < 4; ++i) bP[i] = *(const float4*)(Bb + i * 32);
        }
    };
    auto loadA = [&](int ktb) {
        if (TRANS) {
            const float* Ab = A + (size_t)(k0 + ktb + s_kr) * lda + m0 + s_f4 * 4;
#pragma unroll
            for (int i = 0; i < 4; ++i) aP[i] = *(const float4*)(Ab + i * 32);
        } else {
            const float* Ab = A + (size_t)(m0 + a_r) * lda + k0 + ktb + a_seg * 16;
#pragma unroll
            for (int i = 0; i < 4; ++i) aP[i] = *(const float4*)(Ab + i * 4);
        }
    };

    loadB(0); loadA(0);

    for (int kt = 0; kt < kchunk; kt += 32) {
        __syncthreads();
        if (TRANS) {
#pragma unroll
            for (int i = 0; i < 4; ++i) {
                int m = s_f4 * 4 + i * 32;
                As[m + 0][s_kr] = f2bf(aP[i].x);
                As[m + 1][s_kr] = f2bf(aP[i].y);
                As[m + 2][s_kr] = f2bf(aP[i].z);
                As[m + 3][s_kr] = f2bf(aP[i].w);
            }
        } else {
            bf8v w0, w1;
            w0[0] = (short)f2bf(aP[0].x); w0[1] = (short)f2bf(aP[0].y);
            w0[2] = (short)f2bf(aP[0].z); w0[3] = (short)f2bf(aP[0].w);
            w0[4] = (short)f2bf(aP[1].x); w0[5] = (short)f2bf(aP[1].y);
            w0[6] = (short)f2bf(aP[1].z); w0[7] = (short)f2bf(aP[1].w);
            w1[0] = (short)f2bf(aP[2].x); w1[1] = (short)f2bf(aP[2].y);
            w1[2] = (short)f2bf(aP[2].z); w1[3] = (short)f2bf(aP[2].w);
            w1[4] = (short)f2bf(aP[3].x); w1[5] = (short)f2bf(aP[3].y);
            w1[6] = (short)f2bf(aP[3].z); w1[7] = (short)f2bf(aP[3].w);
            *(bf8v*)&As[a_r][a_seg * 16] = w0;
            *(bf8v*)&As[a_r][a_seg * 16 + 8] = w1;
        }
        if (BTF) {
            *(bf8v*)&Bs[t_n][t_seg * 8] = bPT[0];
            *(bf8v*)&Bs[t_n + 64][t_seg * 8] = bPT[1];
        } else {
#pragma unroll
            for (int i = 0; i < 4; ++i) {
                int n = s_f4 * 4 + i * 32;
                Bs[n + 0][s_kr] = f2bf(bP[i].x);
                Bs[n + 1][s_kr] = f2bf(bP[i].y);
                Bs[n + 2][s_kr] = f2bf(bP[i].z);
                Bs[n + 3][s_kr] = f2bf(bP[i].w);
            }
        }
        __syncthreads();

        if (kt + 32 < kchunk) { loadB(kt + 32); loadA(kt + 32); }

        bf8v af[4], bfv[4];
#pragma unroll
        for (int f = 0; f < 4; ++f) af[f] = *(const bf8v*)&As[wm + f * 16 + r16][kg * 8];
#pragma unroll
        for (int f = 0; f < 4; ++f) bfv[f] = *(const bf8v*)&Bs[wn + f * 16 + r16][kg * 8];
#pragma unroll
        for (int i = 0; i < 4; ++i)
#pragma unroll
            for (int j = 0; j < 4; ++j)
                acc[i][j] = __builtin_amdgcn_mfma_f32_16x16x32_bf16(af[i], bfv[j], acc[i][j], 0, 0, 0);
    }

    const int crow0 = m0 + wm + (lane >> 4) * 4;
#pragma unroll
    for (int i = 0; i < 4; ++i) {
#pragma unroll
        for (int j = 0; j < 4; ++j) {
            float* base = C + (size_t)(crow0 + i * 16) * DOUT + wn + j * 16 + r16;
            base[0 * DOUT] = acc[i][j][0];
            base[1 * DOUT] = acc[i][j][1];
            base[2 * DOUT] = acc[i][j][2];
            base[3 * DOUT] = acc[i][j][3];
        }
    }
}

// Three independent GEMMs co-scheduled, UNIFORM kchunk=512 per block (no tail skew):
// bids [0,256):     adj_s@xs -> C1P[0..8)    (32 mtiles x 8 splits,  k=512)
// bids [256,768):   adj@ys   -> C1P[8..24)   (32 mtiles x 16 splits, k=512)
// bids [768,1792):  adj_t@ys -> C2P[0..16)   (64 mtiles x 16 splits, k=512)
__global__ __launch_bounds__(256)
void gemm_triple_kernel(const float* __restrict__ adj_s,
                        const float* __restrict__ adj,
                        const float* __restrict__ adj_t,
                        const ushort* __restrict__ xsT,
                        const ushort* __restrict__ ysT,
                        float* __restrict__ C1P, float* __restrict__ C2P) {
    __shared__ ushort As[128][40];
    __shared__ ushort Bs[128][40];
    int bid = blockIdx.x;
    if (bid < 256) {
        int s = bid & 7;
        gemm_body<0, 1>(As, Bs, adj_s, NS, nullptr, xsT, NS,
                        C1P + (size_t)s * (NS * DOUT), NS / 8, s * (NS / 8), (bid >> 3) * 128);
    } else if (bid < 768) {
        int b = bid - 256, s = b & 15;
        gemm_body<0, 1>(As, Bs, adj, NT, nullptr, ysT, NT,
                        C1P + (size_t)(8 + s) * (NS * DOUT), NT / 16, s * (NT / 16), (b >> 4) * 128);
    } else {
        int b = bid - 768, s = b & 15;
        gemm_body<0, 1>(As, Bs, adj_t, NT, nullptr, ysT, NT,
                        C2P + (size_t)s * (NT * DOUT), NT / 16, s * (NT / 16), (b >> 4) * 128);
    }
}

// Dependent adj^T @ xns -> C2P[16..24), kchunk=512 (8 splits)
__global__ __launch_bounds__(256)
void gemm_trans_kernel(const float* __restrict__ adj,
                       const float* __restrict__ xns,
                       float* __restrict__ C2P) {
    __shared__ ushort As[128][40];
    __shared__ ushort Bs[128][40];
    int s = blockIdx.y;
    gemm_body<1, 0>(As, Bs, adj, NT, xns, nullptr, 0,
                    C2P + (size_t)(16 + s) * (NT * DOUT), NS / 8, s * (NS / 8), blockIdx.x * 128);
}

// x_new = relu(xs + (sum24 C1P)/rs) -> d_out;  xns = x_new/rs (float4)
__global__ void epilogue1_kernel(const float* __restrict__ C1P,
                                 const float* __restrict__ xs,
                                 const float* __restrict__ rs,
                                 float* __restrict__ outx,
                                 float* __restrict__ xns) {
    int i4 = blockIdx.x * blockDim.x + threadIdx.x;
    if (i4 >= NS * DOUT / 4) return;
    float4 s = ((const float4*)C1P)[i4];
#pragma unroll
    for (int p = 1; p < 24; ++p) {
        float4 v = ((const float4*)(C1P + (size_t)p * (NS * DOUT)))[i4];
        s.x += v.x; s.y += v.y; s.z += v.z; s.w += v.w;
    }
    float r = rs[i4 >> 5];   // (i4*4) / 128
    float4 x = ((const float4*)xs)[i4];
    float4 o, n;
    o.x = fmaxf(x.x + s.x / r, 0.f); n.x = o.x / r;
    o.y = fmaxf(x.y + s.y / r, 0.f); n.y = o.y / r;
    o.z = fmaxf(x.z + s.z / r, 0.f); n.z = o.z / r;
    o.w = fmaxf(x.w + s.w / r, 0.f); n.w = o.w / r;
    ((float4*)outx)[i4] = o;
    ((float4*)xns)[i4] = n;
}

// y_new = relu(ys + (sum24 C2P)/rt) -> d_out + NS*DOUT (float4)
__global__ void epilogue2_kernel(const float* __restrict__ C2P,
                                 const float* __restrict__ ys,
                                 const float* __restrict__ rt,
                                 float* __restrict__ outy) {
    int i4 = blockIdx.x * blockDim.x + threadIdx.x;
    if (i4 >= NT * DOUT / 4) return;
    float4 s = ((const float4*)C2P)[i4];
#pragma unroll
    for (int p = 1; p < 24; ++p) {
        float4 v = ((const float4*)(C2P + (size_t)p * (NT * DOUT)))[i4];
        s.x += v.x; s.y += v.y; s.z += v.z; s.w += v.w;
    }
    float r = rt[i4 >> 5];
    float4 y = ((const float4*)ys)[i4];
    float4 o;
    o.x = fmaxf(y.x + s.x / r, 0.f);
    o.y = fmaxf(y.y + s.y / r, 0.f);
    o.z = fmaxf(y.z + s.z / r, 0.f);
    o.w = fmaxf(y.w + s.w / r, 0.f);
    ((float4*)outy)[i4] = o;
}

extern "C" void kernel_launch(void* const* d_in, const int* in_sizes, int n_in,
                              void* d_out, int out_size, void* d_ws, size_t ws_size,
                              hipStream_t stream) {
    const float* inp_s = (const float*)d_in[0];
    const float* inp_t = (const float*)d_in[1];
    const float* adj   = (const float*)d_in[2];
    const float* adj_s = (const float*)d_in[3];
    const float* adj_t = (const float*)d_in[4];
    const float* W     = (const float*)d_in[5];
    float* out = (float*)d_out;
    float* ws  = (float*)d_ws;

    float* rs    = ws + OFF_RS;
    float* rt    = ws + OFF_RT;
    float* rs0   = ws + OFF_RS0;
    float* prow4 = ws + OFF_PROW4;
    float* ptt   = ws + OFF_PTT;
    float* pta   = ws + OFF_PTA;
    float* pt2   = ws + OFF_PT2;
    float* C1P   = ws + OFF_C1P;
    float* C2P   = ws + OFF_C2P;
    float* xs    = ws + OFF_XS;
    float* ys    = ws + OFF_YS;
    float* xns   = ws + OFF_XNS;
    ushort* xsT  = (ushort*)(ws + OFF_XST);
    ushort* ysT  = (ushort*)(ws + OFF_YST);
    float* u_s   = ws + OFF_US;
    float* u_t   = ws + OFF_UT;

    // Degree pass + independent unscaled projection, co-scheduled (1984 blocks).
    deg_mega_kernel<<<1984, 256, 0, stream>>>(adj, adj_s, adj_t, inp_s, inp_t, W,
                                              rs0, prow4, ptt, pta, u_s, u_t);
    finish_rt1_kernel<<<dim3(NT / 256, 12), 256, 0, stream>>>(ptt, pta, pt2);
    finish_all_kernel<<<(NS + NT) / 256, 256, 0, stream>>>(rs0, prow4, pt2, rs, rt);

    // Cheap scale: xs = u_s/rs (+xsT bf16), ys = u_t/rt (+ysT) — u is only 6 MB.
    scale_kernel<<<(NS + NT) / 64, 256, 0, stream>>>(u_s, u_t, rs, rt, xs, ys, xsT, ysT);

    // Phase A: three GEMMs, uniform 512-K blocks, 1792 blocks = 7/CU.
    gemm_triple_kernel<<<1792, 256, 0, stream>>>(adj_s, adj, adj_t, xsT, ysT, C1P, C2P);
    epilogue1_kernel<<<(NS * DOUT / 4 + 255) / 256, 256, 0, stream>>>(C1P, xs, rs, out, xns);

    // Phase B: dependent adj^T @ xns -> C2P[16..24), 512 blocks.
    gemm_trans_kernel<<<dim3(NT / 128, 8), 256, 0, stream>>>(adj, xns, C2P);
    epilogue2_kernel<<<(NT * DOUT / 4 + 255) / 256, 256, 0, stream>>>(C2P, ys, rt, out + NS * DOUT);
}